// Round 5
// baseline (148.779 us; speedup 1.0000x reference)
//
#include <hip/hip_runtime.h>
#include <math.h>

#define B_  16
#define N_  8192
#define D_  128
#define H_  64
#define E_  64
#define EPSLN 1e-5f

typedef __attribute__((ext_vector_type(8))) short short8;
typedef __attribute__((ext_vector_type(4))) float f32x4;

// workspace layout (bytes):
//   partials : 512*128 f32   @ 0        (262144)
//   Wrt      : H*D bf16      @ 262144   (16384)   Wrt[h][d] = ln_w[d]*Wr[d,h]
//   ug       : H f32         @ 278528   (256)     u[h] = ln_w @ Wr
//   qg       : H f32         @ 278784   (256)     q[h] = ln_b @ Wr
//   W2t      : B*E*H bf16    @ 279040   (131072)  W2t[b][e][h] = ml[h]*Wo[h,e]
//   C2g      : B*E f32       @ 410112   (4096)
//   Zg       : B*N*H bf16    @ 1048576  (16777216)
#define WSB_PART 0
#define WSB_WRT  262144
#define WSB_U    278528
#define WSB_Q    278784
#define WSB_W2T  279040
#define WSB_C2   410112
#define WSB_Z    1048576

static __device__ __forceinline__ unsigned short f2bf(float f) {
    union { float f; unsigned u; } c; c.f = f;
    unsigned u = c.u;
    return (unsigned short)((u + 0x7FFFu + ((u >> 16) & 1u)) >> 16);  // RNE
}
static __device__ __forceinline__ float bf2f(short v) {
    union { unsigned u; float f; } c;
    c.u = ((unsigned)(unsigned short)v) << 16;
    return c.f;
}

// ---------------------------------------------------------------------------
// k_prep (1 block): Wrt (bf16 transposed, ln_w-folded), u, q.
// ---------------------------------------------------------------------------
__global__ __launch_bounds__(256) void k_prep(const float* __restrict__ ln_w,
                                              const float* __restrict__ ln_b,
                                              const float* __restrict__ Wr,
                                              unsigned short* __restrict__ Wrt,
                                              float* __restrict__ ug,
                                              float* __restrict__ qg) {
    __shared__ float ru[4][H_], rq[4][H_];
    int t = threadIdx.x;
    int h = t & 63, dq = t >> 6;
    float u = 0.f, q = 0.f;
    for (int i = 0; i < 32; ++i) {
        int d = dq * 32 + i;
        float wr = Wr[d * H_ + h];          // coalesced across h
        float lw = ln_w[d];
        u += lw * wr;
        q += ln_b[d] * wr;
        Wrt[h * D_ + d] = f2bf(lw * wr);
    }
    ru[dq][h] = u; rq[dq][h] = q;
    __syncthreads();
    if (t < H_) {
        ug[t] = ru[0][t] + ru[1][t] + ru[2][t] + ru[3][t];
        qg[t] = rq[0][t] + rq[1][t] + rq[2][t] + rq[3][t];
    }
}

// ---------------------------------------------------------------------------
// k_pass1: per 256-row tile —
//   stage x -> LDS bf16 (XOR-swizzled 16B granules), LN stats inline;
//   weighted colsum partials (no atomics);
//   MFMA Zraw = (x .* ln_w) @ Wr;  Z = rs*Zraw - rs*mu*u + q -> bf16 global.
// x is read from HBM exactly once in the whole pipeline.
// ---------------------------------------------------------------------------
__global__ __launch_bounds__(256, 2) void k_pass1(const float* __restrict__ x,
                                                  const unsigned short* __restrict__ Wrt,
                                                  const float* __restrict__ ug,
                                                  const float* __restrict__ qg,
                                                  float* __restrict__ partials,
                                                  unsigned short* __restrict__ Zg) {
    __shared__ short xs[256 * 128];            // 64 KB
    __shared__ float mul[256], rsl[256];       // 2 KB
    __shared__ float redc[4][128];             // 2 KB
    __shared__ float ush[H_], qsh[H_];         // 512 B

    int b = blockIdx.y, bx = blockIdx.x, t = threadIdx.x;
    int rowbase = bx * 256;

    if (t < H_) { ush[t] = ug[t]; qsh[t] = qg[t]; }

    // ---- stage row t (fp32 -> bf16 swizzled LDS), stats inline ----
    {
        const float4* xrow = (const float4*)(x + (size_t)(b * N_ + rowbase + t) * D_);
        float s = 0.f, s2 = 0.f;
        int sw = t & 15;
#pragma unroll
        for (int g = 0; g < 16; ++g) {          // 16B granule = 8 bf16
            float4 va = xrow[2 * g], vb = xrow[2 * g + 1];
            s  += (va.x + va.y) + (va.z + va.w) + (vb.x + vb.y) + (vb.z + vb.w);
            s2 += (va.x * va.x + va.y * va.y) + (va.z * va.z + va.w * va.w)
                + (vb.x * vb.x + vb.y * vb.y) + (vb.z * vb.z + vb.w * vb.w);
            short8 sv;
            sv[0] = (short)f2bf(va.x); sv[1] = (short)f2bf(va.y);
            sv[2] = (short)f2bf(va.z); sv[3] = (short)f2bf(va.w);
            sv[4] = (short)f2bf(vb.x); sv[5] = (short)f2bf(vb.y);
            sv[6] = (short)f2bf(vb.z); sv[7] = (short)f2bf(vb.w);
            *(short8*)&xs[t * 128 + ((g ^ sw) * 8)] = sv;
        }
        float mu  = s * (1.f / D_);
        float var = s2 * (1.f / D_) - mu * mu;
        mul[t] = mu;
        rsl[t] = rsqrtf(var + EPSLN);
    }
    __syncthreads();

    // ---- weighted colsum partials from the bf16 tile ----
    {
        int cp = (t & 63) * 2, q = t >> 6;      // q = wave -> r uniform in wave
        int g = cp >> 3, jo = cp & 7;
        float a0 = 0.f, a1 = 0.f;
#pragma unroll 8
        for (int i = 0; i < 64; ++i) {
            int r = q * 64 + i;
            short2 v = *(const short2*)&xs[r * 128 + ((g ^ (r & 15)) * 8) + jo];
            float w = rsl[r], m = mul[r];
            a0 += w * (bf2f(v.x) - m);
            a1 += w * (bf2f(v.y) - m);
        }
        redc[q][cp] = a0;
        redc[q][cp + 1] = a1;
    }
    __syncthreads();
    if (t < 128) {
        float s = redc[0][t] + redc[1][t] + redc[2][t] + redc[3][t];
        partials[(size_t)(b * 32 + bx) * D_ + t] = s;
    }

    // ---- MFMA: Zraw = xs @ Wrt^T  (256x64, K=128) ----
    int wv = t >> 6, lane = t & 63;
    int m16 = lane & 15, quad = lane >> 4;

    f32x4 acc[4][4];
#pragma unroll
    for (int i = 0; i < 4; ++i)
#pragma unroll
        for (int j = 0; j < 4; ++j) acc[i][j] = (f32x4){0.f, 0.f, 0.f, 0.f};

#pragma unroll
    for (int kc = 0; kc < 4; ++kc) {
        short8 af[4], bf[4];
#pragma unroll
        for (int mt = 0; mt < 4; ++mt) {
            int row = wv * 64 + mt * 16 + m16;
            int g = kc * 4 + quad;
            af[mt] = *(const short8*)&xs[row * 128 + ((g ^ m16) * 8)];
        }
#pragma unroll
        for (int nt = 0; nt < 4; ++nt) {
            bf[nt] = *(const short8*)(Wrt + (size_t)(nt * 16 + m16) * D_ + kc * 32 + quad * 8);
        }
#pragma unroll
        for (int mt = 0; mt < 4; ++mt)
#pragma unroll
            for (int nt = 0; nt < 4; ++nt)
                acc[mt][nt] = __builtin_amdgcn_mfma_f32_16x16x32_bf16(
                    af[mt], bf[nt], acc[mt][nt], 0, 0, 0);
    }

    // ---- epilogue: Z = rs*Zraw - rs*mu*u + q -> bf16 ----
    size_t zbase = (size_t)(b * N_ + rowbase) * H_;
#pragma unroll
    for (int mt = 0; mt < 4; ++mt) {
        int rb = wv * 64 + mt * 16 + quad * 4;
        float mu0 = mul[rb + 0], rs0 = rsl[rb + 0];
        float mu1 = mul[rb + 1], rs1 = rsl[rb + 1];
        float mu2 = mul[rb + 2], rs2 = rsl[rb + 2];
        float mu3 = mul[rb + 3], rs3 = rsl[rb + 3];
#pragma unroll
        for (int nt = 0; nt < 4; ++nt) {
            int col = nt * 16 + m16;
            float uc = ush[col], qc = qsh[col];
            unsigned short* zp = Zg + zbase + (size_t)rb * H_ + col;
            zp[0 * H_] = f2bf(rs0 * (acc[mt][nt][0] - mu0 * uc) + qc);
            zp[1 * H_] = f2bf(rs1 * (acc[mt][nt][1] - mu1 * uc) + qc);
            zp[2 * H_] = f2bf(rs2 * (acc[mt][nt][2] - mu2 * uc) + qc);
            zp[3 * H_] = f2bf(rs3 * (acc[mt][nt][3] - mu3 * uc) + qc);
        }
    }
}

// ---------------------------------------------------------------------------
// k_combine2 (one block per batch): partials -> cm -> ml -> W2t (bf16), C2.
// ---------------------------------------------------------------------------
__global__ __launch_bounds__(256) void k_combine2(const float* __restrict__ partials,
                                                  const float* __restrict__ ln_w,
                                                  const float* __restrict__ ln_b,
                                                  const float* __restrict__ Wl,
                                                  const float* __restrict__ bl,
                                                  const float* __restrict__ br,
                                                  const float* __restrict__ Wo,
                                                  const float* __restrict__ bo,
                                                  unsigned short* __restrict__ W2t,
                                                  float* __restrict__ C2g) {
    __shared__ float cm[D_], mlh[H_];
    __shared__ float redC[4][E_];
    int b = blockIdx.x, t = threadIdx.x;

    if (t < D_) {
        float s = 0.f;
#pragma unroll 8
        for (int k = 0; k < 32; ++k)
            s += partials[(size_t)(b * 32 + k) * D_ + t];
        cm[t] = ln_w[t] * s * (1.f / N_) + ln_b[t];
    }
    __syncthreads();
    if (t < H_) {
        float a = bl[t];
        for (int d = 0; d < D_; ++d) a += cm[d] * Wl[d * H_ + t];
        mlh[t] = a;
    }
    __syncthreads();

    // W2t[e][h] = ml[h]*Wo[h,e];  C2[e] = sum_h ml[h]*br[h]*Wo[h,e] + bo[e]
    int e = t & 63, hq = t >> 6;
    float cpart = 0.f;
    size_t wb = (size_t)b * E_ * H_;
    for (int i = 0; i < 16; ++i) {
        int h = hq * 16 + i;
        float wo = Wo[h * E_ + e];              // coalesced across e
        float w2 = mlh[h] * wo;
        cpart += w2 * br[h];
        W2t[wb + (size_t)e * H_ + h] = f2bf(w2);
    }
    redC[hq][e] = cpart;
    __syncthreads();
    if (t < E_)
        C2g[b * E_ + t] = redC[0][t] + redC[1][t] + redC[2][t] + redC[3][t] + bo[t];
}

// ---------------------------------------------------------------------------
// k_pass2: out = Z @ W2 + C2.  Pure MFMA GEMM (256x64, K=64), no LDS tile —
// A-frags straight from Zg (64B-contiguous per wave), B-frags from W2t (L1).
// ---------------------------------------------------------------------------
__global__ __launch_bounds__(256) void k_pass2(const unsigned short* __restrict__ Zg,
                                               const unsigned short* __restrict__ W2t,
                                               const float* __restrict__ C2g,
                                               float* __restrict__ out) {
    __shared__ float C2l[E_];
    int b = blockIdx.y, bx = blockIdx.x, t = threadIdx.x;
    int rowbase = bx * 256;
    if (t < E_) C2l[t] = C2g[b * E_ + t];
    __syncthreads();

    int wv = t >> 6, lane = t & 63;
    int m16 = lane & 15, quad = lane >> 4;

    f32x4 acc[4][4];
#pragma unroll
    for (int i = 0; i < 4; ++i)
#pragma unroll
        for (int j = 0; j < 4; ++j) acc[i][j] = (f32x4){0.f, 0.f, 0.f, 0.f};

    size_t zbase = (size_t)(b * N_ + rowbase) * H_;
    const unsigned short* Wb = W2t + (size_t)b * E_ * H_;

#pragma unroll
    for (int kc = 0; kc < 2; ++kc) {
        short8 af[4], bf[4];
#pragma unroll
        for (int mt = 0; mt < 4; ++mt) {
            int row = wv * 64 + mt * 16 + m16;
            af[mt] = *(const short8*)(Zg + zbase + (size_t)row * H_ + kc * 32 + quad * 8);
        }
#pragma unroll
        for (int nt = 0; nt < 4; ++nt) {
            bf[nt] = *(const short8*)(Wb + (size_t)(nt * 16 + m16) * H_ + kc * 32 + quad * 8);
        }
#pragma unroll
        for (int mt = 0; mt < 4; ++mt)
#pragma unroll
            for (int nt = 0; nt < 4; ++nt)
                acc[mt][nt] = __builtin_amdgcn_mfma_f32_16x16x32_bf16(
                    af[mt], bf[nt], acc[mt][nt], 0, 0, 0);
    }

    size_t outbase = (size_t)(b * N_ + rowbase) * E_;
#pragma unroll
    for (int mt = 0; mt < 4; ++mt) {
        int rb = wv * 64 + mt * 16 + quad * 4;
#pragma unroll
        for (int nt = 0; nt < 4; ++nt) {
            int col = nt * 16 + m16;
            float Cc = C2l[col];
            float* o = out + outbase + (size_t)rb * E_ + col;
            o[0 * E_] = acc[mt][nt][0] + Cc;
            o[1 * E_] = acc[mt][nt][1] + Cc;
            o[2 * E_] = acc[mt][nt][2] + Cc;
            o[3 * E_] = acc[mt][nt][3] + Cc;
        }
    }
}

extern "C" void kernel_launch(void* const* d_in, const int* in_sizes, int n_in,
                              void* d_out, int out_size, void* d_ws, size_t ws_size,
                              hipStream_t stream) {
    const float* x    = (const float*)d_in[0];
    const float* ln_w = (const float*)d_in[1];
    const float* ln_b = (const float*)d_in[2];
    const float* Wl   = (const float*)d_in[3];
    const float* bl   = (const float*)d_in[4];
    const float* Wr   = (const float*)d_in[5];
    const float* br   = (const float*)d_in[6];
    const float* Wo   = (const float*)d_in[7];
    const float* bo   = (const float*)d_in[8];
    float* out = (float*)d_out;
    char* ws   = (char*)d_ws;

    float*          partials = (float*)(ws + WSB_PART);
    unsigned short* Wrt      = (unsigned short*)(ws + WSB_WRT);
    float*          ug       = (float*)(ws + WSB_U);
    float*          qg       = (float*)(ws + WSB_Q);
    unsigned short* W2t      = (unsigned short*)(ws + WSB_W2T);
    float*          C2g      = (float*)(ws + WSB_C2);
    unsigned short* Zg       = (unsigned short*)(ws + WSB_Z);

    k_prep<<<1, 256, 0, stream>>>(ln_w, ln_b, Wr, Wrt, ug, qg);
    k_pass1<<<dim3(32, B_), 256, 0, stream>>>(x, Wrt, ug, qg, partials, Zg);
    k_combine2<<<B_, 256, 0, stream>>>(partials, ln_w, ln_b, Wl, bl, br, Wo,
                                       bo, W2t, C2g);
    k_pass2<<<dim3(32, B_), 256, 0, stream>>>(Zg, W2t, C2g, out);
}